// Round 1
// baseline (74.675 us; speedup 1.0000x reference)
//
#include <hip/hip_runtime.h>
#include <math.h>

#define NB 256
#define NV 2
#define NN 512
#define ND 10
#define THRESH_SQ 6.0f
#define EPS_W 1e-6f

// One block per (b,v). Computes rv[bv] = 0.5*(r_g2s + r_s2g).
__global__ __launch_bounds__(256)
void chamfer_bv(const float* __restrict__ achieved,
                const float* __restrict__ desired,
                float* __restrict__ rv_out)
{
    const int bv  = blockIdx.x;      // 0..511
    const int tid = threadIdx.x;     // 0..255

    __shared__ __align__(16) float s_vis[NN][4];
    __shared__ __align__(16) float g_vis[NN][4];
    __shared__ float s_xy[NN][2];
    __shared__ float g_xy[NN][2];
    __shared__ float s_n2[NN];
    __shared__ float g_n2[NN];
    __shared__ int   cntA[NN];
    __shared__ int   cntB[NN];
    __shared__ float red_f[4];
    __shared__ int   red_g[4];
    __shared__ int   red_l[4];

    const float* sb = achieved + (size_t)bv * NN * ND;
    const float* gb = desired  + (size_t)bv * NN * ND;

    // ---- stage inputs: keep dims [0,2) -> xy, [5,9) -> vis ----
    for (int i = tid; i < NN * ND; i += 256) {
        int n = i / ND;
        int d = i - n * ND;
        float sv = sb[i], gv = gb[i];
        if (d < 2)                 { s_xy[n][d]     = sv; g_xy[n][d]     = gv; }
        else if (d >= 5 && d < 9)  { s_vis[n][d-5]  = sv; g_vis[n][d-5]  = gv; }
    }
    cntA[tid] = 0; cntA[tid + 256] = 0;
    cntB[tid] = 0; cntB[tid + 256] = 0;
    __syncthreads();

    // ---- per-row squared norms ----
    for (int n = tid; n < NN; n += 256) {
        float4 s = *(const float4*)&s_vis[n][0];
        float4 g = *(const float4*)&g_vis[n][0];
        s_n2[n] = s.x*s.x + s.y*s.y + s.z*s.z + s.w*s.w;
        g_n2[n] = g.x*g.x + g.y*g.y + g.z*g.z + g.w*g.w;
    }
    __syncthreads();

    // ============ direction A: queries = goals (m), sources = states (n) ====
    // md1[m] = min_n P[n][m], mi1[m] = argmin (first index).
    // Inner compare uses q = s_n2[n] - 2*dot (g_n2[m] is constant per m).
    const int m0 = tid, m1 = tid + 256;
    float rA = 0.0f, rB = 0.0f;
    {
        float4 q0 = *(const float4*)&g_vis[m0][0];
        float4 q1 = *(const float4*)&g_vis[m1][0];
        float best0 = INFINITY, best1 = INFINITY;
        int bi0 = 0, bi1 = 0;
        #pragma unroll 4
        for (int n = 0; n < NN; ++n) {
            float4 s = *(const float4*)&s_vis[n][0];
            float nn2 = s_n2[n];
            float d0 = fmaf(s.x, q0.x, fmaf(s.y, q0.y, fmaf(s.z, q0.z, s.w*q0.w)));
            float d1 = fmaf(s.x, q1.x, fmaf(s.y, q1.y, fmaf(s.z, q1.z, s.w*q1.w)));
            float p0 = fmaf(-2.0f, d0, nn2);
            float p1 = fmaf(-2.0f, d1, nn2);
            if (p0 < best0) { best0 = p0; bi0 = n; }
            if (p1 < best1) { best1 = p1; bi1 = n; }
        }
        float md0 = best0 + g_n2[m0];
        float md1 = best1 + g_n2[m1];
        bool lat0 = md0 > THRESH_SQ;
        bool lat1 = md1 > THRESH_SQ;
        if (!lat0) atomicAdd(&cntA[bi0], 1);
        if (!lat1) atomicAdd(&cntA[bi1], 1);
        __syncthreads();

        float sum = 0.0f;
        int anyl = (lat0 ? 1 : 0) | (lat1 ? 1 : 0);
        if (!lat0) {
            float dx = g_xy[m0][0] - s_xy[bi0][0];
            float dy = g_xy[m0][1] - s_xy[bi0][1];
            float w  = 1.0f / ((float)cntA[bi0] + EPS_W);
            sum += w * sqrtf(dx*dx + dy*dy);
        }
        if (!lat1) {
            float dx = g_xy[m1][0] - s_xy[bi1][0];
            float dy = g_xy[m1][1] - s_xy[bi1][1];
            float w  = 1.0f / ((float)cntA[bi1] + EPS_W);
            sum += w * sqrtf(dx*dx + dy*dy);
        }
        int grp = (cntA[tid] > 0 ? 1 : 0) + (cntA[tid + 256] > 0 ? 1 : 0);

        #pragma unroll
        for (int off = 32; off > 0; off >>= 1) {
            sum  += __shfl_down(sum, off);
            grp  += __shfl_down(grp, off);
            anyl |= __shfl_down(anyl, off);
        }
        int wid = tid >> 6;
        if ((tid & 63) == 0) { red_f[wid] = sum; red_g[wid] = grp; red_l[wid] = anyl; }
        __syncthreads();
        if (tid == 0) {
            float s = red_f[0] + red_f[1] + red_f[2] + red_f[3];
            int   g = red_g[0] + red_g[1] + red_g[2] + red_g[3];
            int   l = red_l[0] | red_l[1] | red_l[2] | red_l[3];
            float unm    = (float)l;
            float groups = fmaxf((float)g + unm, 1.0f);
            rA = -(s + unm) / groups;
        }
    }

    // ============ direction B: queries = states (n), sources = goals (m) ====
    {
        float4 q0 = *(const float4*)&s_vis[m0][0];
        float4 q1 = *(const float4*)&s_vis[m1][0];
        float best0 = INFINITY, best1 = INFINITY;
        int bi0 = 0, bi1 = 0;
        #pragma unroll 4
        for (int m = 0; m < NN; ++m) {
            float4 g = *(const float4*)&g_vis[m][0];
            float mm2 = g_n2[m];
            float d0 = fmaf(g.x, q0.x, fmaf(g.y, q0.y, fmaf(g.z, q0.z, g.w*q0.w)));
            float d1 = fmaf(g.x, q1.x, fmaf(g.y, q1.y, fmaf(g.z, q1.z, g.w*q1.w)));
            float p0 = fmaf(-2.0f, d0, mm2);
            float p1 = fmaf(-2.0f, d1, mm2);
            if (p0 < best0) { best0 = p0; bi0 = m; }
            if (p1 < best1) { best1 = p1; bi1 = m; }
        }
        float md0 = best0 + s_n2[m0];
        float md1 = best1 + s_n2[m1];
        bool lat0 = md0 > THRESH_SQ;
        bool lat1 = md1 > THRESH_SQ;
        if (!lat0) atomicAdd(&cntB[bi0], 1);
        if (!lat1) atomicAdd(&cntB[bi1], 1);
        __syncthreads();

        float sum = 0.0f;
        int anyl = (lat0 ? 1 : 0) | (lat1 ? 1 : 0);
        if (!lat0) {
            float dx = s_xy[m0][0] - g_xy[bi0][0];
            float dy = s_xy[m0][1] - g_xy[bi0][1];
            float w  = 1.0f / ((float)cntB[bi0] + EPS_W);
            sum += w * sqrtf(dx*dx + dy*dy);
        }
        if (!lat1) {
            float dx = s_xy[m1][0] - g_xy[bi1][0];
            float dy = s_xy[m1][1] - g_xy[bi1][1];
            float w  = 1.0f / ((float)cntB[bi1] + EPS_W);
            sum += w * sqrtf(dx*dx + dy*dy);
        }
        int grp = (cntB[tid] > 0 ? 1 : 0) + (cntB[tid + 256] > 0 ? 1 : 0);

        #pragma unroll
        for (int off = 32; off > 0; off >>= 1) {
            sum  += __shfl_down(sum, off);
            grp  += __shfl_down(grp, off);
            anyl |= __shfl_down(anyl, off);
        }
        int wid = tid >> 6;
        if ((tid & 63) == 0) { red_f[wid] = sum; red_g[wid] = grp; red_l[wid] = anyl; }
        __syncthreads();
        if (tid == 0) {
            float s = red_f[0] + red_f[1] + red_f[2] + red_f[3];
            int   g = red_g[0] + red_g[1] + red_g[2] + red_g[3];
            int   l = red_l[0] | red_l[1] | red_l[2] | red_l[3];
            float unm    = (float)l;
            float groups = fmaxf((float)g + unm, 1.0f);
            rB = -(s + unm) / groups;
        }
    }

    if (tid == 0) rv_out[bv] = 0.5f * (rA + rB);
}

// out[b] = mean over v of rv[b][v]
__global__ void chamfer_finalize(const float* __restrict__ rv, float* __restrict__ out)
{
    int b = blockIdx.x * 256 + threadIdx.x;
    if (b < NB) out[b] = 0.5f * (rv[2*b] + rv[2*b + 1]);
}

extern "C" void kernel_launch(void* const* d_in, const int* in_sizes, int n_in,
                              void* d_out, int out_size, void* d_ws, size_t ws_size,
                              hipStream_t stream)
{
    const float* achieved = (const float*)d_in[0];
    const float* desired  = (const float*)d_in[1];
    float* out = (float*)d_out;
    float* rv  = (float*)d_ws;   // NB*NV floats = 2 KB of scratch

    chamfer_bv<<<NB * NV, 256, 0, stream>>>(achieved, desired, rv);
    chamfer_finalize<<<1, 256, 0, stream>>>(rv, out);
}